// Round 7
// baseline (689.266 us; speedup 1.0000x reference)
//
#include <hip/hip_runtime.h>

typedef __bf16 bf16x8 __attribute__((ext_vector_type(8)));
typedef float f32x4 __attribute__((ext_vector_type(4)));
using u16 = unsigned short;

#define SCALE 0.17677669529663689f  // 32^-0.5

__device__ __forceinline__ u16 f2bf(float f) {
    union { float f; unsigned u; } x; x.f = f;
    unsigned r = x.u + 0x7fffu + ((x.u >> 16) & 1u);
    return (u16)(r >> 16);
}
__device__ __forceinline__ unsigned pk2(float a, float b) {
    return (unsigned)f2bf(a) | ((unsigned)f2bf(b) << 16);
}

// ---------------------------------------------------------------- prep ------
__global__ __launch_bounds__(256) void prep_k(
    const float* __restrict__ q_w, const float* __restrict__ kv_w,
    const float* __restrict__ p_w, const float* __restrict__ f1w,
    const float* __restrict__ f2w, const float* __restrict__ rel,
    u16* __restrict__ qwt, u16* __restrict__ kvwt, u16* __restrict__ pwt,
    u16* __restrict__ f1wt, u16* __restrict__ f2wt, float* __restrict__ biasF)
{
    int t = blockIdx.x * 256 + threadIdx.x;
    if (t < 65536) {                                   // q_w  256x256
        int k = t & 255, n = t >> 8;
        qwt[t] = f2bf(q_w[k * 256 + n]);
    } else if (t < 196608) {                           // kv_w 256x512
        int u = t - 65536; int k = u & 255, n = u >> 8;
        kvwt[u] = f2bf(kv_w[k * 512 + n]);
    } else if (t < 262144) {                           // proj_w 256x256
        int u = t - 196608; int k = u & 255, n = u >> 8;
        pwt[u] = f2bf(p_w[k * 256 + n]);
    } else if (t < 524288) {                           // fc1_w 256x1024
        int u = t - 262144; int k = u & 255, n = u >> 8;
        f1wt[u] = f2bf(f1w[k * 1024 + n]);
    } else if (t < 786432) {                           // fc2_w 1024x256
        int u = t - 524288; int k = u & 1023, n = u >> 10;
        f2wt[u] = f2bf(f2w[k * 256 + n]);
    } else if (t < 819200) {                           // biasF 8*16*64*4 (swapped frag)
        int u = t - 786432;
        int r = u & 3, l = (u >> 2) & 63, fr = (u >> 8) & 15, h = u >> 12;
        int fi = fr >> 2, fj = fr & 3;
        int m = fi * 16 + (l & 15);
        int n = fj * 16 + 4 * (l >> 4) + r;
        int idx = ((m >> 3) - (n >> 3) + 7) * 15 + ((m & 7) - (n & 7) + 7);
        biasF[u] = rel[idx * 8 + h];
    }
}

// ----------------------------------------------------------- layernorm ------
template <int PART>
__global__ __launch_bounds__(256) void ln_k(
    const float* __restrict__ xa, const float* __restrict__ xb,
    const float* __restrict__ gw, const float* __restrict__ bw,
    u16* __restrict__ oa, u16* __restrict__ ob)
{
    int lane = threadIdx.x & 63, wid = threadIdx.x >> 6;
    int r = blockIdx.x * 4 + wid;
    const float* src; u16* dst; int row;
    if constexpr (PART) {
        if (r < 65536) { src = xa; dst = oa; row = r; }
        else           { src = xb; dst = ob; row = r - 65536; }
    } else { src = xa; dst = oa; row = r; }

    float4 v = *(const float4*)(src + (size_t)row * 256 + lane * 4);
    float s = v.x + v.y + v.z + v.w;
    float q = v.x * v.x + v.y * v.y + v.z * v.z + v.w * v.w;
    #pragma unroll
    for (int m = 1; m < 64; m <<= 1) {
        s += __shfl_xor(s, m, 64);
        q += __shfl_xor(q, m, 64);
    }
    float mean = s * (1.0f / 256.0f);
    float var  = q * (1.0f / 256.0f) - mean * mean;
    float rstd = rsqrtf(var + 1e-5f);
    float4 gg = *(const float4*)(gw + lane * 4);
    float4 bb = *(const float4*)(bw + lane * 4);

    int orow = row;
    if constexpr (PART) {  // window partition: (b,h,w) -> (b, wi, n)
        int b_ = row >> 12, l = row & 4095;
        int hh = l >> 6, ww = l & 63;
        int wi = (hh >> 3) * 8 + (ww >> 3);
        int n  = (hh & 7) * 8 + (ww & 7);
        orow = b_ * 4096 + wi * 64 + n;
    }
    ushort4 o;
    o.x = f2bf((v.x - mean) * rstd * gg.x + bb.x);
    o.y = f2bf((v.y - mean) * rstd * gg.y + bb.y);
    o.z = f2bf((v.z - mean) * rstd * gg.z + bb.z);
    o.w = f2bf((v.w - mean) * rstd * gg.w + bb.w);
    *(ushort4*)(dst + (size_t)orow * 256 + lane * 4) = o;
}

// ------------------------------------------------- all-register GEMM --------
// C[M][N] = A[M][KD] @ Bt[N][KD]^T + bias.  ZERO LDS, ZERO barriers.
// Block = 4 independent waves. Wave w: rows [bx*256 + w*64, +64),
// cols [by*32, +32). B-frags global->VGPR (64 VGPR per 256-K chunk,
// L2-resident weights); A-frags global->VGPR per k-slice; compiler
// software-pipelines freely (no sync points). Swapped mfma(B,A):
// lane&15 = m, regs = 4 consecutive n -> wide stores.
// EPI: 0 bf16, 1 gelu->bf16, 2 proj(+window-reverse+resid)->f32,
//      3 +resid->f32.
template <int KD, int NCOLS, int EPI>
__global__ __launch_bounds__(256) void gemm_reg(
    const u16* __restrict__ A, const u16* __restrict__ Bt,
    const float* __restrict__ bias, u16* __restrict__ obf,
    float* __restrict__ of32, const float* __restrict__ res)
{
    const int t = threadIdx.x, lane = t & 63, w = t >> 6;
    const int g = lane >> 4, c = lane & 15;
    const int bm = blockIdx.x * 256 + w * 64;
    const int bn = blockIdx.y * 32;

    const u16* Ap = A  + (size_t)(bm + c) * KD + g * 8;   // + i*16*KD + k
    const u16* Bp = Bt + (size_t)(bn + c) * KD + g * 8;   // + j*16*KD + k

    f32x4 acc[4][2];
    #pragma unroll
    for (int i = 0; i < 4; i++) { acc[i][0] = (f32x4){0,0,0,0}; acc[i][1] = (f32x4){0,0,0,0}; }

    #pragma unroll
    for (int kc = 0; kc < KD; kc += 256) {
        bf16x8 bf[2][8];
        #pragma unroll
        for (int j = 0; j < 2; j++)
            #pragma unroll
            for (int ks = 0; ks < 8; ks++)
                bf[j][ks] = *(const bf16x8*)(Bp + (size_t)j * 16 * KD + kc + ks * 32);
        #pragma unroll
        for (int ks = 0; ks < 8; ks++) {
            bf16x8 af[4];
            #pragma unroll
            for (int i = 0; i < 4; i++)
                af[i] = *(const bf16x8*)(Ap + (size_t)i * 16 * KD + kc + ks * 32);
            #pragma unroll
            for (int i = 0; i < 4; i++)
                #pragma unroll
                for (int j = 0; j < 2; j++)
                    acc[i][j] = __builtin_amdgcn_mfma_f32_16x16x32_bf16(
                        bf[j][ks], af[i], acc[i][j], 0, 0, 0);
        }
    }

    // epilogue: lane c = m, regs = 4 consecutive n
    #pragma unroll
    for (int i = 0; i < 4; i++) {
        int row = bm + i * 16 + c;
        #pragma unroll
        for (int j = 0; j < 2; j++) {
            int col = bn + j * 16 + 4 * g;
            float4 b4 = *(const float4*)(bias + col);
            float v0 = acc[i][j][0] + b4.x;
            float v1 = acc[i][j][1] + b4.y;
            float v2 = acc[i][j][2] + b4.z;
            float v3 = acc[i][j][3] + b4.w;
            if constexpr (EPI == 0) {
                uint2 pk = { pk2(v0, v1), pk2(v2, v3) };
                *(uint2*)(obf + (size_t)row * NCOLS + col) = pk;
            } else if constexpr (EPI == 1) {
                float g0 = 0.5f * v0 * (1.f + erff(v0 * 0.70710678118654752f));
                float g1 = 0.5f * v1 * (1.f + erff(v1 * 0.70710678118654752f));
                float g2 = 0.5f * v2 * (1.f + erff(v2 * 0.70710678118654752f));
                float g3 = 0.5f * v3 * (1.f + erff(v3 * 0.70710678118654752f));
                uint2 pk = { pk2(g0, g1), pk2(g2, g3) };
                *(uint2*)(obf + (size_t)row * NCOLS + col) = pk;
            } else if constexpr (EPI == 2) {  // proj: window-reverse + resid
                int b_ = row >> 12, wi = (row >> 6) & 63, n = row & 63;
                int hh = (wi >> 3) * 8 + (n >> 3);
                int ww = (wi & 7) * 8 + (n & 7);
                size_t nrow = (size_t)b_ * 4096 + hh * 64 + ww;
                float4 r4 = *(const float4*)(res + nrow * 256 + col);
                float4 ov = { v0 + r4.x, v1 + r4.y, v2 + r4.z, v3 + r4.w };
                *(float4*)(of32 + nrow * 256 + col) = ov;
            } else {                           // fc2: + resid -> f32
                float4 r4 = *(const float4*)(res + (size_t)row * 256 + col);
                float4 ov = { v0 + r4.x, v1 + r4.y, v2 + r4.z, v3 + r4.w };
                *(float4*)(of32 + (size_t)row * 256 + col) = ov;
            }
        }
    }
}

// ----------------------------------------------------------- attention ------
__global__ __launch_bounds__(256) void attn_k(
    const u16* __restrict__ Q, const u16* __restrict__ KV,
    const float* __restrict__ biasF, u16* __restrict__ O)
{
    __shared__ __align__(16) u16 Pl[4][64 * 64];
    __shared__ __align__(16) u16 Vt[4][32 * 80];
    const int t = threadIdx.x, lane = t & 63, w = t >> 6;
    const int g = lane >> 4, c = lane & 15;
    const int pair = blockIdx.x * 4 + w;
    const int win = pair >> 3, head = pair & 7;
    const size_t qbase  = (size_t)win * 64 * 256 + head * 32;
    const size_t kvbase = (size_t)win * 64 * 512 + head * 32;

    u16* vt = &Vt[w][0];
    {
        const u16* vp = KV + kvbase + 256 + (size_t)lane * 512;
        uint4 v0 = *(const uint4*)(vp);
        uint4 v1 = *(const uint4*)(vp + 8);
        uint4 v2 = *(const uint4*)(vp + 16);
        uint4 v3 = *(const uint4*)(vp + 24);
#define SCAT(vv, dbase)                                           \
        vt[(dbase + 0) * 80 + lane] = (u16)(vv.x);                \
        vt[(dbase + 1) * 80 + lane] = (u16)(vv.x >> 16);          \
        vt[(dbase + 2) * 80 + lane] = (u16)(vv.y);                \
        vt[(dbase + 3) * 80 + lane] = (u16)(vv.y >> 16);          \
        vt[(dbase + 4) * 80 + lane] = (u16)(vv.z);                \
        vt[(dbase + 5) * 80 + lane] = (u16)(vv.z >> 16);          \
        vt[(dbase + 6) * 80 + lane] = (u16)(vv.w);                \
        vt[(dbase + 7) * 80 + lane] = (u16)(vv.w >> 16);
        SCAT(v0, 0) SCAT(v1, 8) SCAT(v2, 16) SCAT(v3, 24)
#undef SCAT
    }

    bf16x8 qf[4], kf[4];
    #pragma unroll
    for (int i = 0; i < 4; i++) {
        qf[i] = *(const bf16x8*)(Q  + qbase  + (size_t)(i * 16 + c) * 256 + 8 * g);
        kf[i] = *(const bf16x8*)(KV + kvbase + (size_t)(i * 16 + c) * 512 + 8 * g);
    }
    f32x4 s[4][4];
    #pragma unroll
    for (int i = 0; i < 4; i++)
        #pragma unroll
        for (int j = 0; j < 4; j++) {
            s[i][j] = (f32x4){0.f, 0.f, 0.f, 0.f};
            s[i][j] = __builtin_amdgcn_mfma_f32_16x16x32_bf16(kf[j], qf[i], s[i][j], 0, 0, 0);
        }

    #pragma unroll
    for (int i = 0; i < 4; i++)
        #pragma unroll
        for (int j = 0; j < 4; j++) {
            f32x4 bf4 = *(const f32x4*)(biasF + ((size_t)(head * 16 + i * 4 + j) * 64 + lane) * 4);
            #pragma unroll
            for (int r = 0; r < 4; r++) s[i][j][r] = s[i][j][r] * SCALE + bf4[r];
        }

    #pragma unroll
    for (int i = 0; i < 4; i++) {
        float mx = -1e30f;
        #pragma unroll
        for (int j = 0; j < 4; j++)
            #pragma unroll
            for (int r = 0; r < 4; r++) mx = fmaxf(mx, s[i][j][r]);
        mx = fmaxf(mx, __shfl_xor(mx, 16, 64));
        mx = fmaxf(mx, __shfl_xor(mx, 32, 64));
        float sum = 0.f;
        #pragma unroll
        for (int j = 0; j < 4; j++)
            #pragma unroll
            for (int r = 0; r < 4; r++) {
                float e = __expf(s[i][j][r] - mx);
                s[i][j][r] = e; sum += e;
            }
        sum += __shfl_xor(sum, 16, 64);
        sum += __shfl_xor(sum, 32, 64);
        float inv = 1.f / sum;
        #pragma unroll
        for (int j = 0; j < 4; j++)
            #pragma unroll
            for (int r = 0; r < 4; r++) s[i][j][r] *= inv;
    }

    u16* pl = &Pl[w][0];
    #pragma unroll
    for (int i = 0; i < 4; i++) {
        int m = i * 16 + c;
        #pragma unroll
        for (int j = 0; j < 4; j++) {
            int kbyte = 32 * j + 8 * g;
            uint2 pk = { pk2(s[i][j][0], s[i][j][1]), pk2(s[i][j][2], s[i][j][3]) };
            *(uint2*)((char*)pl + m * 128 + (kbyte ^ ((m & 7) << 4))) = pk;
        }
    }

    f32x4 o[4][2];
    #pragma unroll
    for (int i = 0; i < 4; i++) { o[i][0] = (f32x4){0,0,0,0}; o[i][1] = (f32x4){0,0,0,0}; }
    #pragma unroll
    for (int ks = 0; ks < 2; ks++) {
        bf16x8 pa[4], vb[2];
        #pragma unroll
        for (int i = 0; i < 4; i++) {
            int row = i * 16 + c;
            int ch = (ks * 4 + g) ^ (row & 7);
            pa[i] = *(const bf16x8*)((char*)pl + row * 128 + ch * 16);
        }
        #pragma unroll
        for (int j = 0; j < 2; j++) {
            int d = j * 16 + c;
            vb[j] = *(const bf16x8*)(vt + d * 80 + ks * 32 + 8 * g);
        }
        #pragma unroll
        for (int i = 0; i < 4; i++)
            #pragma unroll
            for (int j = 0; j < 2; j++)
                o[i][j] = __builtin_amdgcn_mfma_f32_16x16x32_bf16(vb[j], pa[i], o[i][j], 0, 0, 0);
    }

    #pragma unroll
    for (int i = 0; i < 4; i++) {
        size_t row = (size_t)win * 64 + i * 16 + c;
        #pragma unroll
        for (int j = 0; j < 2; j++) {
            int col = head * 32 + j * 16 + 4 * g;
            uint2 pk = { pk2(o[i][j][0], o[i][j][1]), pk2(o[i][j][2], o[i][j][3]) };
            *(uint2*)(O + row * 256 + col) = pk;
        }
    }
}

// -------------------------------------------------------------- launch ------
// Workspace layout (peak 203.4 MB):
//   [0,       2.10M)  weights: qwt kvwt pwt f1wt f2wt biasF
//   [2.10M,  35.65M)  x1w  -> attn -> xln
//   [35.65M, 69.21M)  x2w
//   [69.21M,136.31M)  Qb  -> xbuf f32 (after attn)
//   [102.76M,169.87M) KVb
//   [136.31M,203.42M) h1 half-buffer (fc1/fc2 in two row-halves)
extern "C" void kernel_launch(void* const* d_in, const int* in_sizes, int n_in,
                              void* d_out, int out_size, void* d_ws, size_t ws_size,
                              hipStream_t stream)
{
    const float* x1  = (const float*)d_in[0];
    const float* x2  = (const float*)d_in[1];
    const float* n1g = (const float*)d_in[2];
    const float* n1b = (const float*)d_in[3];
    const float* q_w = (const float*)d_in[4];
    const float* q_b = (const float*)d_in[5];
    const float* kv_w= (const float*)d_in[6];
    const float* kv_b= (const float*)d_in[7];
    const float* p_w = (const float*)d_in[8];
    const float* p_b = (const float*)d_in[9];
    const float* rel = (const float*)d_in[10];
    const float* n3g = (const float*)d_in[11];
    const float* n3b = (const float*)d_in[12];
    const float* f1w = (const float*)d_in[13];
    const float* f1b = (const float*)d_in[14];
    const float* f2w = (const float*)d_in[15];
    const float* f2b = (const float*)d_in[16];

    char* ws = (char*)d_ws;
    u16*   qwt   = (u16*)(ws + 0);
    u16*   kvwt  = (u16*)(ws + 131072);
    u16*   pwt   = (u16*)(ws + 393216);
    u16*   f1wt  = (u16*)(ws + 524288);
    u16*   f2wt  = (u16*)(ws + 1048576);
    float* biasF = (float*)(ws + 1572864);

    u16*   x1w  = (u16*)(ws + 2097152);
    u16*   x2w  = (u16*)(ws + 35651584);
    u16*   Qb   = (u16*)(ws + 69206016);
    u16*   KVb  = (u16*)(ws + 102760448);
    u16*   attn = (u16*)(ws + 2097152);     // overlays x1w
    float* xbuf = (float*)(ws + 69206016);  // overlays Qb/KVb
    u16*   xln  = (u16*)(ws + 2097152);     // overlays attn
    u16*   h1   = (u16*)(ws + 136314880);   // 67.1 MB half-buffer

    float* out = (float*)d_out;

    prep_k<<<3200, 256, 0, stream>>>(q_w, kv_w, p_w, f1w, f2w, rel,
                                     qwt, kvwt, pwt, f1wt, f2wt, biasF);
    ln_k<1><<<32768, 256, 0, stream>>>(x1, x2, n1g, n1b, x1w, x2w);
    gemm_reg<256, 256, 0><<<dim3(256, 8), 256, 0, stream>>>(x1w, qwt, q_b, Qb, nullptr, nullptr);
    gemm_reg<256, 512, 0><<<dim3(256, 16), 256, 0, stream>>>(x2w, kvwt, kv_b, KVb, nullptr, nullptr);
    attn_k<<<2048, 256, 0, stream>>>(Qb, KVb, biasF, attn);
    gemm_reg<256, 256, 2><<<dim3(256, 8), 256, 0, stream>>>(attn, pwt, p_b, nullptr, xbuf, x1);
    ln_k<0><<<16384, 256, 0, stream>>>(xbuf, nullptr, n3g, n3b, xln, nullptr);
    // fc1+fc2 in two row-halves (h1 = 67 MB half-buffer)
    gemm_reg<256, 1024, 1><<<dim3(128, 32), 256, 0, stream>>>(xln, f1wt, f1b, h1, nullptr, nullptr);
    gemm_reg<1024, 256, 3><<<dim3(128, 8), 256, 0, stream>>>(h1, f2wt, f2b, nullptr, out, xbuf);
    gemm_reg<256, 1024, 1><<<dim3(128, 32), 256, 0, stream>>>(xln + (size_t)32768 * 256, f1wt, f1b, h1, nullptr, nullptr);
    gemm_reg<1024, 256, 3><<<dim3(128, 8), 256, 0, stream>>>(h1, f2wt, f2b, nullptr, out + (size_t)32768 * 256, xbuf + (size_t)32768 * 256);
}

// Round 8
// 317.097 us; speedup vs baseline: 2.1737x; 2.1737x over previous
//
#include <hip/hip_runtime.h>

typedef __bf16 bf16x8 __attribute__((ext_vector_type(8)));
typedef float f32x4 __attribute__((ext_vector_type(4)));
using u16 = unsigned short;

#define SCALE 0.17677669529663689f  // 32^-0.5

// Direct HBM->LDS DMA, 16B per lane (dest linear: base + lane*16).
#define GLOAD16(lp, gp)                                                        \
    __builtin_amdgcn_global_load_lds(                                          \
        (const __attribute__((address_space(1))) void*)(gp),                   \
        (__attribute__((address_space(3))) void*)(lp), 16, 0, 0)

__device__ __forceinline__ u16 f2bf(float f) {
    union { float f; unsigned u; } x; x.f = f;
    unsigned r = x.u + 0x7fffu + ((x.u >> 16) & 1u);
    return (u16)(r >> 16);
}
__device__ __forceinline__ unsigned pk2(float a, float b) {
    return (unsigned)f2bf(a) | ((unsigned)f2bf(b) << 16);
}
__device__ __forceinline__ float gelu_t(float x) {
    float u = 0.7978845608028654f * (x + 0.044715f * x * x * x);
    float e = __expf(2.f * u);
    float th = 1.f - 2.f / (e + 1.f);          // tanh(u), overflow-safe
    return 0.5f * x * (1.f + th);
}

// ---------------------------------------------------------------- prep ------
// qwt/kvwt/pwt: Wt[N][K] bf16 (for gemm_k). f1p/f2p: fragment-packed bf16
// (frag (ng,ks): lane l holds W[k=32ks+8(l>>4)+e][n=16ng+(l&15)]).
// biasF: rel-pos bias in swapped C-frag layout.
__global__ __launch_bounds__(256) void prep_k(
    const float* __restrict__ q_w, const float* __restrict__ kv_w,
    const float* __restrict__ p_w, const float* __restrict__ f1w,
    const float* __restrict__ f2w, const float* __restrict__ rel,
    u16* __restrict__ qwt, u16* __restrict__ kvwt, u16* __restrict__ pwt,
    u16* __restrict__ f1p, u16* __restrict__ f2p, float* __restrict__ biasF)
{
    int t = blockIdx.x * 256 + threadIdx.x;
    if (t < 65536) {                                   // q_w  256x256
        int k = t & 255, n = t >> 8;
        qwt[t] = f2bf(q_w[k * 256 + n]);
    } else if (t < 196608) {                           // kv_w 256x512
        int u = t - 65536; int k = u & 255, n = u >> 8;
        kvwt[u] = f2bf(kv_w[k * 512 + n]);
    } else if (t < 262144) {                           // proj_w 256x256
        int u = t - 196608; int k = u & 255, n = u >> 8;
        pwt[u] = f2bf(p_w[k * 256 + n]);
    } else if (t < 524288) {                           // f1p packed frags
        int u = t - 262144;
        int e = u & 7, l = (u >> 3) & 63, ks = (u >> 9) & 7, ng = u >> 12;
        int k = ks * 32 + (l >> 4) * 8 + e;
        int n = ng * 16 + (l & 15);
        f1p[u] = f2bf(f1w[k * 1024 + n]);
    } else if (t < 786432) {                           // f2p packed frags
        int u = t - 524288;
        int e = u & 7, l = (u >> 3) & 63, ks = (u >> 9) & 31, ng = u >> 14;
        int k = ks * 32 + (l >> 4) * 8 + e;
        int n = ng * 16 + (l & 15);
        f2p[u] = f2bf(f2w[k * 256 + n]);
    } else if (t < 819200) {                           // biasF 8*16*64*4
        int u = t - 786432;
        int r = u & 3, l = (u >> 2) & 63, fr = (u >> 8) & 15, h = u >> 12;
        int fi = fr >> 2, fj = fr & 3;
        int m = fi * 16 + (l & 15);
        int n = fj * 16 + 4 * (l >> 4) + r;
        int idx = ((m >> 3) - (n >> 3) + 7) * 15 + ((m & 7) - (n & 7) + 7);
        biasF[u] = rel[idx * 8 + h];
    }
}

// ----------------------------------------------------------- layernorm ------
// One wave per 256-elem row; two streams + window-partition permute.
__global__ __launch_bounds__(256) void ln_k(
    const float* __restrict__ xa, const float* __restrict__ xb,
    const float* __restrict__ gw, const float* __restrict__ bw,
    u16* __restrict__ oa, u16* __restrict__ ob)
{
    int lane = threadIdx.x & 63, wid = threadIdx.x >> 6;
    int r = blockIdx.x * 4 + wid;
    const float* src; u16* dst; int row;
    if (r < 65536) { src = xa; dst = oa; row = r; }
    else           { src = xb; dst = ob; row = r - 65536; }

    float4 v = *(const float4*)(src + (size_t)row * 256 + lane * 4);
    float s = v.x + v.y + v.z + v.w;
    float q = v.x * v.x + v.y * v.y + v.z * v.z + v.w * v.w;
    #pragma unroll
    for (int m = 1; m < 64; m <<= 1) {
        s += __shfl_xor(s, m, 64);
        q += __shfl_xor(q, m, 64);
    }
    float mean = s * (1.0f / 256.0f);
    float var  = q * (1.0f / 256.0f) - mean * mean;
    float rstd = rsqrtf(var + 1e-5f);
    float4 gg = *(const float4*)(gw + lane * 4);
    float4 bb = *(const float4*)(bw + lane * 4);

    int b_ = row >> 12, l = row & 4095;
    int hh = l >> 6, ww = l & 63;
    int wi = (hh >> 3) * 8 + (ww >> 3);
    int n  = (hh & 7) * 8 + (ww & 7);
    int orow = b_ * 4096 + wi * 64 + n;

    ushort4 o;
    o.x = f2bf((v.x - mean) * rstd * gg.x + bb.x);
    o.y = f2bf((v.y - mean) * rstd * gg.y + bb.y);
    o.z = f2bf((v.z - mean) * rstd * gg.z + bb.z);
    o.w = f2bf((v.w - mean) * rstd * gg.w + bb.w);
    *(ushort4*)(dst + (size_t)orow * 256 + lane * 4) = o;
}

// ---------------------------------------------------------------- GEMM ------
// (R5-verified) 128x128 tile, BK=64, 2-phase dbuf global_load_lds, swapped
// mfma(B,A) -> wide stores. EPI: 0 bf16 out, 2 proj(+window-rev+resid)->f32.
template <int NCOLS, int KD, int EPI>
__global__ __launch_bounds__(256) void gemm_k(
    const u16* __restrict__ A, const u16* __restrict__ Bt,
    const float* __restrict__ bias, u16* __restrict__ obf,
    float* __restrict__ of32, const float* __restrict__ res)
{
    __shared__ __align__(16) u16 As[2][128 * 64];
    __shared__ __align__(16) u16 Bs[2][128 * 64];
    const int t = threadIdx.x;
    const int lane = t & 63, w = t >> 6;
    const int wm = w >> 1, wn = w & 1;
    const int g = lane >> 4, c = lane & 15;
    const int bm = blockIdx.x * 128;
    const int bn = blockIdx.y * 128;
    const int r_in = lane >> 3;
    const int slot = lane & 7;
    const int gch  = slot ^ r_in;

    const u16* Ab = A  + (size_t)bm * KD + gch * 8;
    const u16* Bb = Bt + (size_t)bn * KD + gch * 8;

    f32x4 acc[4][4];
    #pragma unroll
    for (int i = 0; i < 4; i++)
        #pragma unroll
        for (int j = 0; j < 4; j++) acc[i][j] = (f32x4){0.f, 0.f, 0.f, 0.f};

#define STAGE(buf, k0)                                                        \
    {                                                                         \
        _Pragma("unroll")                                                     \
        for (int i_ = 0; i_ < 4; i_++) {                                      \
            const int rowbase = w * 32 + i_ * 8;                              \
            GLOAD16(&As[buf][rowbase * 64],                                   \
                    Ab + (size_t)(rowbase + r_in) * KD + (k0));               \
            GLOAD16(&Bs[buf][rowbase * 64],                                   \
                    Bb + (size_t)(rowbase + r_in) * KD + (k0));               \
        }                                                                     \
    }

#define COMPUTE(buf)                                                          \
    {                                                                         \
        _Pragma("unroll")                                                     \
        for (int kk = 0; kk < 2; kk++) {                                      \
            bf16x8 af[4], bfr[4];                                             \
            _Pragma("unroll")                                                 \
            for (int i_ = 0; i_ < 4; i_++) {                                  \
                int ra = wm * 64 + i_ * 16 + c;                               \
                af[i_]  = *(const bf16x8*)(&As[buf][ra * 64 + ((kk * 4 + g) ^ (ra & 7)) * 8]); \
                int rb = wn * 64 + i_ * 16 + c;                               \
                bfr[i_] = *(const bf16x8*)(&Bs[buf][rb * 64 + ((kk * 4 + g) ^ (rb & 7)) * 8]); \
            }                                                                 \
            _Pragma("unroll")                                                 \
            for (int i_ = 0; i_ < 4; i_++)                                    \
                _Pragma("unroll")                                             \
                for (int j_ = 0; j_ < 4; j_++)                                \
                    acc[i_][j_] = __builtin_amdgcn_mfma_f32_16x16x32_bf16(    \
                        bfr[j_], af[i_], acc[i_][j_], 0, 0, 0);               \
        }                                                                     \
    }

    STAGE(0, 0);
    __syncthreads();
    for (int k0 = 0; k0 < KD; k0 += 128) {
        STAGE(1, k0 + 64);
        COMPUTE(0);
        __syncthreads();
        if (k0 + 128 < KD) STAGE(0, k0 + 128);
        COMPUTE(1);
        if (k0 + 128 < KD) __syncthreads();
    }
#undef STAGE
#undef COMPUTE

    #pragma unroll
    for (int i = 0; i < 4; i++) {
        int row = bm + wm * 64 + i * 16 + c;
        #pragma unroll
        for (int j = 0; j < 4; j++) {
            int col = bn + wn * 64 + j * 16 + 4 * g;
            float4 b4 = *(const float4*)(bias + col);
            float v0 = acc[i][j][0] + b4.x;
            float v1 = acc[i][j][1] + b4.y;
            float v2 = acc[i][j][2] + b4.z;
            float v3 = acc[i][j][3] + b4.w;
            if constexpr (EPI == 0) {
                uint2 pk = { pk2(v0, v1), pk2(v2, v3) };
                *(uint2*)(obf + (size_t)row * NCOLS + col) = pk;
            } else {  // proj: window-reverse + residual -> f32
                int b_ = row >> 12, wi = (row >> 6) & 63, n = row & 63;
                int hh = (wi >> 3) * 8 + (n >> 3);
                int ww = (wi & 7) * 8 + (n & 7);
                size_t nrow = (size_t)b_ * 4096 + hh * 64 + ww;
                float4 r4 = *(const float4*)(res + nrow * 256 + col);
                float4 ov = { v0 + r4.x, v1 + r4.y, v2 + r4.z, v3 + r4.w };
                *(float4*)(of32 + nrow * 256 + col) = ov;
            }
        }
    }
}

// ----------------------------------------------------------- attention ------
__global__ __launch_bounds__(256) void attn_k(
    const u16* __restrict__ Q, const u16* __restrict__ KV,
    const float* __restrict__ biasF, u16* __restrict__ O)
{
    __shared__ __align__(16) u16 Pl[4][64 * 64];
    __shared__ __align__(16) u16 Vt[4][32 * 80];
    const int t = threadIdx.x, lane = t & 63, w = t >> 6;
    const int g = lane >> 4, c = lane & 15;
    const int pair = blockIdx.x * 4 + w;
    const int win = pair >> 3, head = pair & 7;
    const size_t qbase  = (size_t)win * 64 * 256 + head * 32;
    const size_t kvbase = (size_t)win * 64 * 512 + head * 32;

    u16* vt = &Vt[w][0];
    {
        const u16* vp = KV + kvbase + 256 + (size_t)lane * 512;
        uint4 v0 = *(const uint4*)(vp);
        uint4 v1 = *(const uint4*)(vp + 8);
        uint4 v2 = *(const uint4*)(vp + 16);
        uint4 v3 = *(const uint4*)(vp + 24);
#define SCAT(vv, dbase)                                           \
        vt[(dbase + 0) * 80 + lane] = (u16)(vv.x);                \
        vt[(dbase + 1) * 80 + lane] = (u16)(vv.x >> 16);          \
        vt[(dbase + 2) * 80 + lane] = (u16)(vv.y);                \
        vt[(dbase + 3) * 80 + lane] = (u16)(vv.y >> 16);          \
        vt[(dbase + 4) * 80 + lane] = (u16)(vv.z);                \
        vt[(dbase + 5) * 80 + lane] = (u16)(vv.z >> 16);          \
        vt[(dbase + 6) * 80 + lane] = (u16)(vv.w);                \
        vt[(dbase + 7) * 80 + lane] = (u16)(vv.w >> 16);
        SCAT(v0, 0) SCAT(v1, 8) SCAT(v2, 16) SCAT(v3, 24)
#undef SCAT
    }

    bf16x8 qf[4], kf[4];
    #pragma unroll
    for (int i = 0; i < 4; i++) {
        qf[i] = *(const bf16x8*)(Q  + qbase  + (size_t)(i * 16 + c) * 256 + 8 * g);
        kf[i] = *(const bf16x8*)(KV + kvbase + (size_t)(i * 16 + c) * 512 + 8 * g);
    }
    f32x4 s[4][4];
    #pragma unroll
    for (int i = 0; i < 4; i++)
        #pragma unroll
        for (int j = 0; j < 4; j++) {
            s[i][j] = (f32x4){0.f, 0.f, 0.f, 0.f};
            s[i][j] = __builtin_amdgcn_mfma_f32_16x16x32_bf16(kf[j], qf[i], s[i][j], 0, 0, 0);
        }

    #pragma unroll
    for (int i = 0; i < 4; i++)
        #pragma unroll
        for (int j = 0; j < 4; j++) {
            f32x4 bf4 = *(const f32x4*)(biasF + ((size_t)(head * 16 + i * 4 + j) * 64 + lane) * 4);
            #pragma unroll
            for (int r = 0; r < 4; r++) s[i][j][r] = s[i][j][r] * SCALE + bf4[r];
        }

    #pragma unroll
    for (int i = 0; i < 4; i++) {
        float mx = -1e30f;
        #pragma unroll
        for (int j = 0; j < 4; j++)
            #pragma unroll
            for (int r = 0; r < 4; r++) mx = fmaxf(mx, s[i][j][r]);
        mx = fmaxf(mx, __shfl_xor(mx, 16, 64));
        mx = fmaxf(mx, __shfl_xor(mx, 32, 64));
        float sum = 0.f;
        #pragma unroll
        for (int j = 0; j < 4; j++)
            #pragma unroll
            for (int r = 0; r < 4; r++) {
                float e = __expf(s[i][j][r] - mx);
                s[i][j][r] = e; sum += e;
            }
        sum += __shfl_xor(sum, 16, 64);
        sum += __shfl_xor(sum, 32, 64);
        float inv = 1.f / sum;
        #pragma unroll
        for (int j = 0; j < 4; j++)
            #pragma unroll
            for (int r = 0; r < 4; r++) s[i][j][r] *= inv;
    }

    u16* pl = &Pl[w][0];
    #pragma unroll
    for (int i = 0; i < 4; i++) {
        int m = i * 16 + c;
        #pragma unroll
        for (int j = 0; j < 4; j++) {
            int kbyte = 32 * j + 8 * g;
            uint2 pk = { pk2(s[i][j][0], s[i][j][1]), pk2(s[i][j][2], s[i][j][3]) };
            *(uint2*)((char*)pl + m * 128 + (kbyte ^ ((m & 7) << 4))) = pk;
        }
    }

    f32x4 o[4][2];
    #pragma unroll
    for (int i = 0; i < 4; i++) { o[i][0] = (f32x4){0,0,0,0}; o[i][1] = (f32x4){0,0,0,0}; }
    #pragma unroll
    for (int ks = 0; ks < 2; ks++) {
        bf16x8 pa[4], vb[2];
        #pragma unroll
        for (int i = 0; i < 4; i++) {
            int row = i * 16 + c;
            int ch = (ks * 4 + g) ^ (row & 7);
            pa[i] = *(const bf16x8*)((char*)pl + row * 128 + ch * 16);
        }
        #pragma unroll
        for (int j = 0; j < 2; j++) {
            int d = j * 16 + c;
            vb[j] = *(const bf16x8*)(vt + d * 80 + ks * 32 + 8 * g);
        }
        #pragma unroll
        for (int i = 0; i < 4; i++)
            #pragma unroll
            for (int j = 0; j < 2; j++)
                o[i][j] = __builtin_amdgcn_mfma_f32_16x16x32_bf16(vb[j], pa[i], o[i][j], 0, 0, 0);
    }

    #pragma unroll
    for (int i = 0; i < 4; i++) {
        size_t row = (size_t)win * 64 + i * 16 + c;
        #pragma unroll
        for (int j = 0; j < 2; j++) {
            int col = head * 32 + j * 16 + 4 * g;
            uint2 pk = { pk2(o[i][j][0], o[i][j][1]), pk2(o[i][j][2], o[i][j][3]) };
            *(uint2*)(O + row * 256 + col) = pk;
        }
    }
}

// ------------------------------------------------------------ MLP mega ------
// out = x + fc2(gelu(fc1(LN(x)))) for 64 rows per block. Hidden never
// touches HBM: 4 chunks of 256 cols through a 32KB LDS tile. Weights read
// as packed fragments (coalesced 1KB/wave, L2-resident). 64KB LDS ->
// 2 blocks/CU. Barriers amortized over ~128 MFMA each.
__global__ __launch_bounds__(256, 2) void mlp_mega(
    const float* __restrict__ xin, const float* __restrict__ gw,
    const float* __restrict__ bw, const bf16x8* __restrict__ f1p,
    const bf16x8* __restrict__ f2p, const float* __restrict__ f1b,
    const float* __restrict__ f2b, float* __restrict__ out)
{
    __shared__ __align__(16) u16 SM[2][64 * 256];   // [0]=Xl, [1]=Hl; f32 bounce view
    u16* Xl = &SM[0][0];
    u16* Hl = &SM[1][0];
    float* Fb = (float*)&SM[0][0];
    const int t = threadIdx.x, lane = t & 63, w = t >> 6;
    const int g = lane >> 4, c = lane & 15;
    const int m0 = blockIdx.x * 64;

    // ---- LN3 inline: wave w handles rows w*16..+15, write Xl swizzled ----
    {
        float4 gg = *(const float4*)(gw + lane * 4);
        float4 bb = *(const float4*)(bw + lane * 4);
        for (int it = 0; it < 16; it++) {
            int row = w * 16 + it;
            float4 v = *(const float4*)(xin + (size_t)(m0 + row) * 256 + lane * 4);
            float s = v.x + v.y + v.z + v.w;
            float q = v.x * v.x + v.y * v.y + v.z * v.z + v.w * v.w;
            #pragma unroll
            for (int m = 1; m < 64; m <<= 1) {
                s += __shfl_xor(s, m, 64);
                q += __shfl_xor(q, m, 64);
            }
            float mean = s * (1.0f / 256.0f);
            float var  = q * (1.0f / 256.0f) - mean * mean;
            float rstd = rsqrtf(var + 1e-5f);
            float n0 = (v.x - mean) * rstd * gg.x + bb.x;
            float n1 = (v.y - mean) * rstd * gg.y + bb.y;
            float n2 = (v.z - mean) * rstd * gg.z + bb.z;
            float n3 = (v.w - mean) * rstd * gg.w + bb.w;
            uint2 pk = { pk2(n0, n1), pk2(n2, n3) };
            *(uint2*)((char*)Xl + row * 512 + ((((lane >> 1) ^ (row & 7)) << 4))
                      + ((lane & 1) << 3)) = pk;
        }
    }
    __syncthreads();

    f32x4 acc2[4][4];
    #pragma unroll
    for (int i = 0; i < 4; i++)
        #pragma unroll
        for (int n = 0; n < 4; n++) acc2[i][n] = (f32x4){0, 0, 0, 0};

    #pragma unroll
    for (int hc = 0; hc < 4; hc++) {
        // ---- fc1: h[64 rows][wave's 64 cols] of this 256-wide chunk ----
        f32x4 acc1[4][4];
        #pragma unroll
        for (int i = 0; i < 4; i++)
            #pragma unroll
            for (int n = 0; n < 4; n++) acc1[i][n] = (f32x4){0, 0, 0, 0};
        #pragma unroll
        for (int ks = 0; ks < 8; ks++) {
            bf16x8 bfr[4], af[4];
            #pragma unroll
            for (int n = 0; n < 4; n++)
                bfr[n] = f1p[(size_t)((hc * 16 + w * 4 + n) * 8 + ks) * 64 + lane];
            #pragma unroll
            for (int i = 0; i < 4; i++) {
                int row = i * 16 + c;
                af[i] = *(const bf16x8*)((char*)Xl + row * 512
                                         + (((4 * ks + g) ^ (row & 7)) << 4));
            }
            #pragma unroll
            for (int i = 0; i < 4; i++)
                #pragma unroll
                for (int n = 0; n < 4; n++)
                    acc1[i][n] = __builtin_amdgcn_mfma_f32_16x16x32_bf16(
                        bfr[n], af[i], acc1[i][n], 0, 0, 0);
        }
        // gelu + bias -> Hl (swizzled)
        #pragma unroll
        for (int i = 0; i < 4; i++) {
            int row = i * 16 + c;
            #pragma unroll
            for (int n = 0; n < 4; n++) {
                float4 b4 = *(const float4*)(f1b + hc * 256 + w * 64 + n * 16 + 4 * g);
                float h0 = gelu_t(acc1[i][n][0] + b4.x);
                float h1 = gelu_t(acc1[i][n][1] + b4.y);
                float h2 = gelu_t(acc1[i][n][2] + b4.z);
                float h3 = gelu_t(acc1[i][n][3] + b4.w);
                uint2 pk = { pk2(h0, h1), pk2(h2, h3) };
                int cq = 8 * w + 2 * n + (g >> 1);
                *(uint2*)((char*)Hl + row * 512 + (((cq ^ (row & 7)) << 4))
                          + ((g & 1) << 3)) = pk;
            }
        }
        __syncthreads();
        // ---- fc2: acc2 += h_chunk @ f2w_chunk ----
        #pragma unroll
        for (int ks = 0; ks < 8; ks++) {
            bf16x8 bfr[4], ah[4];
            #pragma unroll
            for (int n = 0; n < 4; n++)
                bfr[n] = f2p[(size_t)((w * 4 + n) * 32 + hc * 8 + ks) * 64 + lane];
            #pragma unroll
            for (int i = 0; i < 4; i++) {
                int row = i * 16 + c;
                ah[i] = *(const bf16x8*)((char*)Hl + row * 512
                                         + (((4 * ks + g) ^ (row & 7)) << 4));
            }
            #pragma unroll
            for (int i = 0; i < 4; i++)
                #pragma unroll
                for (int n = 0; n < 4; n++)
                    acc2[i][n] = __builtin_amdgcn_mfma_f32_16x16x32_bf16(
                        bfr[n], ah[i], acc2[i][n], 0, 0, 0);
        }
        __syncthreads();
    }

    // ---- bounce acc2 -> f32 LDS (swizzled), then coalesced epilogue ----
    #pragma unroll
    for (int i = 0; i < 4; i++) {
        int row = i * 16 + c;
        #pragma unroll
        for (int n = 0; n < 4; n++) {
            int cq = 16 * w + 4 * n + g;
            *(f32x4*)((char*)Fb + row * 1024 + (((cq ^ (row & 7)) << 4))) = acc2[i][n];
        }
    }
    __syncthreads();
    {
        float4 b2 = *(const float4*)(f2b + lane * 4);
        for (int it = 0; it < 16; it++) {
            int row = w * 16 + it;
            f32x4 hv = *(const f32x4*)((char*)Fb + row * 1024
                                       + (((lane ^ (row & 7)) << 4)));
            float4 rv = *(const float4*)(xin + (size_t)(m0 + row) * 256 + lane * 4);
            float4 ov = { hv[0] + b2.x + rv.x, hv[1] + b2.y + rv.y,
                          hv[2] + b2.z + rv.z, hv[3] + b2.w + rv.w };
            *(float4*)(out + (size_t)(m0 + row) * 256 + lane * 4) = ov;
        }
    }
}

// -------------------------------------------------------------- launch ------
// Workspace (peak ~137 MB):
//   [0,       2.10M)  weights: qwt kvwt pwt f1p f2p biasF
//   [2.10M,  35.65M)  x1w -> attn (after Q gemm)
//   [35.65M, 69.21M)  x2w
//   [69.21M,136.31M)  Qb -> xbuf f32 (after attn)
//   [102.76M,169.87M) KVb
extern "C" void kernel_launch(void* const* d_in, const int* in_sizes, int n_in,
                              void* d_out, int out_size, void* d_ws, size_t ws_size,
                              hipStream_t stream)
{
    const float* x1  = (const float*)d_in[0];
    const float* x2  = (const float*)d_in[1];
    const float* n1g = (const float*)d_in[2];
    const float* n1b = (const float*)d_in[3];
    const float* q_w = (const float*)d_in[4];
    const float* q_b = (const float*)d_in[5];
    const float* kv_w= (const float*)d_in[6];
    const float* kv_b= (const float*)d_in[7];
    const float* p_w = (const float*)d_in[8];
    const float* p_b = (const float*)d_in[9];
    const float* rel = (const float*)d_in[10];
    const float* n3g = (const float*)d_in[11];
    const float* n3b = (const float*)d_in[12];
    const float* f1w = (const float*)d_in[13];
    const float* f1b = (const float*)d_in[14];
    const float* f2w = (const float*)d_in[15];
    const float* f2b = (const float*)d_in[16];

    char* ws = (char*)d_ws;
    u16*   qwt   = (u16*)(ws + 0);
    u16*   kvwt  = (u16*)(ws + 131072);
    u16*   pwt   = (u16*)(ws + 393216);
    u16*   f1p   = (u16*)(ws + 524288);
    u16*   f2p   = (u16*)(ws + 1048576);
    float* biasF = (float*)(ws + 1572864);

    u16*   x1w  = (u16*)(ws + 2097152);
    u16*   x2w  = (u16*)(ws + 35651584);
    u16*   Qb   = (u16*)(ws + 69206016);
    u16*   KVb  = (u16*)(ws + 102760448);
    u16*   attn = (u16*)(ws + 2097152);     // overlays x1w (dead after Q gemm)
    float* xbuf = (float*)(ws + 69206016);  // overlays Qb/KVb (dead after attn)

    float* out = (float*)d_out;

    prep_k<<<3200, 256, 0, stream>>>(q_w, kv_w, p_w, f1w, f2w, rel,
                                     qwt, kvwt, pwt, f1p, f2p, biasF);
    ln_k<<<32768, 256, 0, stream>>>(x1, x2, n1g, n1b, x1w, x2w);
    gemm_k<256, 256, 0><<<dim3(512, 2), 256, 0, stream>>>(x1w, qwt, q_b, Qb, nullptr, nullptr);
    gemm_k<512, 256, 0><<<dim3(512, 4), 256, 0, stream>>>(x2w, kvwt, kv_b, KVb, nullptr, nullptr);
    attn_k<<<2048, 256, 0, stream>>>(Qb, KVb, biasF, attn);
    gemm_k<256, 256, 2><<<dim3(512, 2), 256, 0, stream>>>(attn, pwt, p_b, nullptr, xbuf, x1);
    mlp_mega<<<1024, 256, 0, stream>>>(xbuf, n3g, n3b, (const bf16x8*)f1p,
                                       (const bf16x8*)f2p, f1b, f2b, out);
}